// Round 9
// baseline (229.667 us; speedup 1.0000x reference)
//
#include <hip/hip_runtime.h>

#define T_TOT 2304
#define S_LEN 128
#define D_IN  1024
#define D_H   64
#define BATCH 2
#define NROW  (BATCH * T_TOT)
#define SCALE 0.125f
#define KCHUNKS 8
#define KCW   (D_IN / KCHUNKS)   // 128
#define TB    16                 // t-rows per flash block
#define FCH0  256                // s-chunk width
#define NSC0  9                  // number of s-chunks
#define NTBLK (T_TOT / TB)       // 144
#define NT16  (T_TOT / 16)       // 144 col-tiles
#define NPART (NSC0 * 4)         // 36 partials per t-block

typedef unsigned short u16;
typedef __attribute__((ext_vector_type(8))) short short8;
typedef __attribute__((ext_vector_type(4))) float f32x4;
typedef __attribute__((ext_vector_type(4))) unsigned short u16x4;

static __device__ __forceinline__ u16 f2bf(float f) {
    unsigned u = __float_as_uint(f);
    unsigned r = (u + 0x7fffu + ((u >> 16) & 1u)) >> 16;
    return (u16)r;
}
static __device__ __forceinline__ float bf2f(u16 s) {
    return __uint_as_float((unsigned)s << 16);
}

// ---------------------------------------------------------------------------
// Kernel 1a: LayerNorm(x_row) -> xn hi/lo (split bf16). One block (256)/row.
// ---------------------------------------------------------------------------
__global__ __launch_bounds__(256) void k_ln(
    const float* __restrict__ x,
    const float* __restrict__ ln_g,  const float* __restrict__ ln_b,
    const float* __restrict__ ln_gs, const float* __restrict__ ln_bs,
    const float* __restrict__ ln_ge, const float* __restrict__ ln_be,
    u16* __restrict__ xn_hi, u16* __restrict__ xn_lo)
{
    __shared__ float red1[256], red2[256];
    const int row = blockIdx.x;
    const int t = row % T_TOT;
    const int tid = threadIdx.x;

    const float *gg, *bb;
    if (t < S_LEN)               { gg = ln_gs; bb = ln_bs; }
    else if (t >= T_TOT - S_LEN) { gg = ln_ge; bb = ln_be; }
    else                         { gg = ln_g;  bb = ln_b;  }

    const float4 xv = *(const float4*)(x + (size_t)row * D_IN + 4 * tid);
    float s  = xv.x + xv.y + xv.z + xv.w;
    float s2 = xv.x * xv.x + xv.y * xv.y + xv.z * xv.z + xv.w * xv.w;
    red1[tid] = s; red2[tid] = s2; __syncthreads();
    for (int off = 128; off > 0; off >>= 1) {
        if (tid < off) { red1[tid] += red1[tid + off]; red2[tid] += red2[tid + off]; }
        __syncthreads();
    }
    const float mean = red1[0] * (1.f / D_IN);
    const float var  = red2[0] * (1.f / D_IN) - mean * mean;
    const float rstd = rsqrtf(var + 1e-5f);

    const float4 gv = *(const float4*)(gg + 4 * tid);
    const float4 bv = *(const float4*)(bb + 4 * tid);
    float o0 = (xv.x - mean) * rstd * gv.x + bv.x;
    float o1 = (xv.y - mean) * rstd * gv.y + bv.y;
    float o2 = (xv.z - mean) * rstd * gv.z + bv.z;
    float o3 = (xv.w - mean) * rstd * gv.w + bv.w;

    u16x4 hv, lv;
    hv[0] = f2bf(o0); lv[0] = f2bf(o0 - bf2f(hv[0]));
    hv[1] = f2bf(o1); lv[1] = f2bf(o1 - bf2f(hv[1]));
    hv[2] = f2bf(o2); lv[2] = f2bf(o2 - bf2f(hv[2]));
    hv[3] = f2bf(o3); lv[3] = f2bf(o3 - bf2f(hv[3]));
    *(u16x4*)(xn_hi + (size_t)row * D_IN + 4 * tid) = hv;
    *(u16x4*)(xn_lo + (size_t)row * D_IN + 4 * tid) = lv;
}

// ---------------------------------------------------------------------------
// Kernel 1b: prep — transpose+split Wh/Whs/Whe, and split cope_emb^T
// ---------------------------------------------------------------------------
#define WPREP_N (3 * D_H * D_IN)
__global__ __launch_bounds__(256) void k_prep(
    const float* __restrict__ Wh, const float* __restrict__ Whs, const float* __restrict__ Whe,
    const float* __restrict__ cope,
    u16* __restrict__ wT_hi, u16* __restrict__ wT_lo,
    u16* __restrict__ cT_hi, u16* __restrict__ cT_lo)
{
    const int gid = blockIdx.x * 256 + threadIdx.x;
    if (gid < WPREP_N) {
        const int seg = gid >> 16;
        const int o = gid & 65535;
        const int j = o >> 10, k = o & 1023;
        const float* W = seg == 0 ? Wh : (seg == 1 ? Whs : Whe);
        const float f = W[k * D_H + j];
        const u16 hi = f2bf(f);
        wT_hi[gid] = hi;
        wT_lo[gid] = f2bf(f - bf2f(hi));
    } else {
        const int idx = gid - WPREP_N;
        if (idx < T_TOT * D_H) {
            const int n = idx >> 6, d = idx & 63;
            const float f = cope[(size_t)d * T_TOT + n];
            const u16 hi = f2bf(f);
            cT_hi[idx] = hi;
            cT_lo[idx] = f2bf(f - bf2f(hi));
        }
    }
}

// ---------------------------------------------------------------------------
// Kernel 1c: h_part[kc] = LN(x)[:, kc*128:+128] @ W_seg[kc chunk]  (MFMA, split)
// ---------------------------------------------------------------------------
__global__ __launch_bounds__(256) void k_hgemm(
    const u16* __restrict__ xn_hi, const u16* __restrict__ xn_lo,
    const u16* __restrict__ wT_hi, const u16* __restrict__ wT_lo,
    float* __restrict__ h_part)
{
    const int tile = blockIdx.x;              // 0..71
    const int kc   = blockIdx.y;              // 0..7
    const int k0   = kc * KCW;
    const int tt = tile % 36;
    const int seg = tt < 2 ? 1 : (tt >= 34 ? 2 : 0);

    __shared__ u16 Bh[64 * KCW];
    __shared__ u16 Bl[64 * KCW];

    const int tid = threadIdx.x;
    {
        const int r = tid >> 2;
        const int c0 = (tid & 3) * 32;
        const u16* sh = wT_hi + ((size_t)seg * D_H + r) * D_IN + k0 + c0;
        const u16* sl = wT_lo + ((size_t)seg * D_H + r) * D_IN + k0 + c0;
        const int sw = (r & 7) << 3;
        #pragma unroll
        for (int u = 0; u < 4; ++u) {
            const int col = c0 + 8 * u;
            *(short8*)&Bh[r * KCW + (col ^ sw)] = *(const short8*)(sh + 8 * u);
            *(short8*)&Bl[r * KCW + (col ^ sw)] = *(const short8*)(sl + 8 * u);
        }
    }
    __syncthreads();

    const int w = tid >> 6;
    const int lane = tid & 63;
    const int l15 = lane & 15, lg4 = lane >> 4;
    const int row0 = tile * 64 + w * 16;

    const size_t abase = (size_t)(row0 + l15) * D_IN + k0 + 8 * lg4;
    f32x4 acc[4] = {};

    #pragma unroll
    for (int kk = 0; kk < KCW / 32; ++kk) {
        short8 ah = *(const short8*)(xn_hi + abase + kk * 32);
        short8 al = *(const short8*)(xn_lo + abase + kk * 32);
        #pragma unroll
        for (int j = 0; j < 4; ++j) {
            const int brow = j * 16 + l15;
            const int col = (kk * 32 + 8 * lg4) ^ ((brow & 7) << 3);
            short8 bh = *(const short8*)&Bh[brow * KCW + col];
            short8 bl = *(const short8*)&Bl[brow * KCW + col];
            acc[j] = __builtin_amdgcn_mfma_f32_16x16x32_bf16(al, bh, acc[j], 0, 0, 0);
            acc[j] = __builtin_amdgcn_mfma_f32_16x16x32_bf16(ah, bl, acc[j], 0, 0, 0);
            acc[j] = __builtin_amdgcn_mfma_f32_16x16x32_bf16(ah, bh, acc[j], 0, 0, 0);
        }
    }
    float* hp = h_part + (size_t)kc * ((size_t)NROW * D_H);
    #pragma unroll
    for (int j = 0; j < 4; ++j)
        #pragma unroll
        for (int r = 0; r < 4; ++r)
            hp[(size_t)(row0 + 4 * lg4 + r) * D_H + j * 16 + l15] = acc[j][r];
}

// ---------------------------------------------------------------------------
// Kernel 1d: h = sum_kc h_part[kc]
// ---------------------------------------------------------------------------
__global__ __launch_bounds__(256) void k_hred(
    const float* __restrict__ h_part, float* __restrict__ h)
{
    const size_t idx = (size_t)blockIdx.x * 256 + threadIdx.x;
    const size_t N = (size_t)NROW * D_H;
    float s = 0.f;
    #pragma unroll
    for (int kc = 0; kc < KCHUNKS; ++kc) s += h_part[kc * N + idx];
    h[idx] = s;
}

// ---------------------------------------------------------------------------
// Kernel 2: q/k/v projections.
// ---------------------------------------------------------------------------
template <bool SPLIT>
__global__ __launch_bounds__(192) void k_qkv(
    const float* __restrict__ hin,
    const float* __restrict__ Wk,  const float* __restrict__ Wq,  const float* __restrict__ Wv,
    const float* __restrict__ Wks, const float* __restrict__ Wqs, const float* __restrict__ Wvs,
    const float* __restrict__ Wke, const float* __restrict__ Wqe, const float* __restrict__ Wve,
    u16* __restrict__ q_hi, u16* __restrict__ q_lo,
    u16* __restrict__ k_hi, u16* __restrict__ k_lo,
    u16* __restrict__ vT)
{
    __shared__ float hr[D_H];
    const int bid = blockIdx.x;
    const int b = bid / T_TOT, t = bid % T_TOT;
    const int tid = threadIdx.x;

    const float* hrow = hin + ((size_t)b * T_TOT + t) * D_H;
    if (tid < D_H) hr[tid] = hrow[tid];
    __syncthreads();

    const int which = tid >> 6, j = tid & 63;
    const float* W;
    if (t < S_LEN)               W = which == 0 ? Wks : (which == 1 ? Wqs : Wvs);
    else if (t >= T_TOT - S_LEN) W = which == 0 ? Wke : (which == 1 ? Wqe : Wve);
    else                         W = which == 0 ? Wk  : (which == 1 ? Wq  : Wv);

    float acc = 0.f;
    #pragma unroll
    for (int d = 0; d < D_H; ++d) acc += hr[d] * W[d * D_H + j];

    const size_t idx = ((size_t)b * T_TOT + t) * D_H + j;
    u16 hi = f2bf(acc);
    if (which == 0) {
        k_hi[idx] = hi;
        if (SPLIT) k_lo[idx] = f2bf(acc - bf2f(hi));
    } else if (which == 1) {
        q_hi[idx] = hi;
        if (SPLIT) q_lo[idx] = f2bf(acc - bf2f(hi));
    } else {
        vT[((size_t)b * D_H + j) * T_TOT + t] = hi;
    }
}

// ---------------------------------------------------------------------------
// k_lint: lint = q . cope^T (3-term split). Grid (36, 36, 2); wave 16t x 64s.
// ---------------------------------------------------------------------------
__global__ __launch_bounds__(256) void k_lint(
    const u16* __restrict__ a_hi, const u16* __restrict__ a_lo,
    const u16* __restrict__ c_hi, const u16* __restrict__ c_lo,
    float* __restrict__ lint)
{
    const int b  = blockIdx.z;
    const int s0 = blockIdx.x * 64;
    const int t0 = blockIdx.y * 64 + (threadIdx.x >> 6) * 16;
    const int lane = threadIdx.x & 63;
    const int l15 = lane & 15, lg4 = lane >> 4;

    const size_t a_off = ((size_t)(b * T_TOT + t0 + l15)) * D_H + 8 * lg4;
    const short8 ah0 = *(const short8*)(a_hi + a_off);
    const short8 ah1 = *(const short8*)(a_hi + a_off + 32);
    const short8 al0 = *(const short8*)(a_lo + a_off);
    const short8 al1 = *(const short8*)(a_lo + a_off + 32);

    float* o = lint + ((size_t)(b * T_TOT + t0 + 4 * lg4)) * T_TOT + s0 + l15;

    #pragma unroll
    for (int ni = 0; ni < 4; ++ni) {
        const size_t b_off = ((size_t)(s0 + ni * 16 + l15)) * D_H + 8 * lg4;
        short8 bh0 = *(const short8*)(c_hi + b_off);
        short8 bh1 = *(const short8*)(c_hi + b_off + 32);
        short8 bl0 = *(const short8*)(c_lo + b_off);
        short8 bl1 = *(const short8*)(c_lo + b_off + 32);
        f32x4 acc = {0.f, 0.f, 0.f, 0.f};
        acc = __builtin_amdgcn_mfma_f32_16x16x32_bf16(al0, bh0, acc, 0, 0, 0);
        acc = __builtin_amdgcn_mfma_f32_16x16x32_bf16(al1, bh1, acc, 0, 0, 0);
        acc = __builtin_amdgcn_mfma_f32_16x16x32_bf16(ah0, bl0, acc, 0, 0, 0);
        acc = __builtin_amdgcn_mfma_f32_16x16x32_bf16(ah1, bl1, acc, 0, 0, 0);
        acc = __builtin_amdgcn_mfma_f32_16x16x32_bf16(ah0, bh0, acc, 0, 0, 0);
        acc = __builtin_amdgcn_mfma_f32_16x16x32_bf16(ah1, bh1, acc, 0, 0, 0);
        #pragma unroll
        for (int r = 0; r < 4; ++r)
            o[(size_t)r * T_TOT + ni * 16] = acc[r];
    }
}

// ---------------------------------------------------------------------------
// k_gates: dense QK^T (3-term), reduce sigmoid per 16-col tile -> csum.
// Grid (36, 36, 2); wave 16t x 64s. csum[b][t][NT16] fp32.
// ---------------------------------------------------------------------------
__global__ __launch_bounds__(256) void k_gates(
    const u16* __restrict__ a_hi, const u16* __restrict__ a_lo,
    const u16* __restrict__ k_hi, const u16* __restrict__ k_lo,
    float* __restrict__ csum)
{
    const int b  = blockIdx.z;
    const int s0 = blockIdx.x * 64;
    const int t0 = blockIdx.y * 64 + (threadIdx.x >> 6) * 16;
    const int lane = threadIdx.x & 63;
    const int l15 = lane & 15, lg4 = lane >> 4;

    const size_t a_off = ((size_t)(b * T_TOT + t0 + l15)) * D_H + 8 * lg4;
    const short8 ah0 = *(const short8*)(a_hi + a_off);
    const short8 ah1 = *(const short8*)(a_hi + a_off + 32);
    const short8 al0 = *(const short8*)(a_lo + a_off);
    const short8 al1 = *(const short8*)(a_lo + a_off + 32);

    const u16* bh = k_hi + (size_t)b * (T_TOT * D_H);
    const u16* bl = k_lo + (size_t)b * (T_TOT * D_H);

    #pragma unroll
    for (int ni = 0; ni < 4; ++ni) {
        const size_t b_off = ((size_t)(s0 + ni * 16 + l15)) * D_H + 8 * lg4;
        short8 bh0 = *(const short8*)(bh + b_off);
        short8 bh1 = *(const short8*)(bh + b_off + 32);
        short8 bl0 = *(const short8*)(bl + b_off);
        short8 bl1 = *(const short8*)(bl + b_off + 32);
        f32x4 acc = {0.f, 0.f, 0.f, 0.f};
        acc = __builtin_amdgcn_mfma_f32_16x16x32_bf16(al0, bh0, acc, 0, 0, 0);
        acc = __builtin_amdgcn_mfma_f32_16x16x32_bf16(al1, bh1, acc, 0, 0, 0);
        acc = __builtin_amdgcn_mfma_f32_16x16x32_bf16(ah0, bl0, acc, 0, 0, 0);
        acc = __builtin_amdgcn_mfma_f32_16x16x32_bf16(ah1, bl1, acc, 0, 0, 0);
        acc = __builtin_amdgcn_mfma_f32_16x16x32_bf16(ah0, bh0, acc, 0, 0, 0);
        acc = __builtin_amdgcn_mfma_f32_16x16x32_bf16(ah1, bh1, acc, 0, 0, 0);
        const int c16 = (s0 >> 4) + ni;
        #pragma unroll
        for (int r = 0; r < 4; ++r) {
            float g = 1.f / (1.f + __expf(-acc[r]));
            g += __shfl_xor(g, 1); g += __shfl_xor(g, 2);
            g += __shfl_xor(g, 4); g += __shfl_xor(g, 8);
            if (l15 == 0)
                csum[((size_t)(b * T_TOT + t0 + 4 * lg4 + r)) * NT16 + c16] = g;
        }
    }
}

// ---------------------------------------------------------------------------
// k_cscan: per-row exclusive prefix of csum tiles + total.
// ---------------------------------------------------------------------------
__global__ __launch_bounds__(256) void k_cscan(
    const float* __restrict__ csum, float* __restrict__ csumP,
    float* __restrict__ totalv)
{
    const int row = blockIdx.x * 256 + threadIdx.x;   // < NROW
    const size_t base = (size_t)row * NT16;
    float run = 0.f;
    for (int c = 0; c < NT16; ++c) {
        csumP[base + c] = run;
        run += csum[base + c];
    }
    totalv[row] = run;
}

// ---------------------------------------------------------------------------
// k_fattn0: iter-0 flash with CoPE. s-split grid (144, 9, 2); wave span 64.
// Recomputes QK^T tiles (3-term), gates + within-16 scan + csumP base -> pos,
// gathers bias from lint (global), online softmax + PV. Writes {m,d,O}.
// ---------------------------------------------------------------------------
__global__ __launch_bounds__(256) void k_fattn0(
    const u16* __restrict__ q_hi, const u16* __restrict__ q_lo,
    const u16* __restrict__ k_hi, const u16* __restrict__ k_lo,
    const u16* __restrict__ vT,
    const float* __restrict__ lint, const float* __restrict__ csumP,
    const float* __restrict__ totalv,
    float* __restrict__ fM, float* __restrict__ fD, float* __restrict__ fO)
{
    __shared__ u16 pstage[4][TB][32];

    const int b   = blockIdx.z;
    const int scn = blockIdx.y;
    const int bx  = blockIdx.x;
    const int t0 = bx * TB;
    const int t_max = t0 + TB - 1;
    if (scn * FCH0 > t_max) return;

    const int tid = threadIdx.x;
    const int wid = tid >> 6;
    const int lane = tid & 63;
    const int l15 = lane & 15, lg4 = lane >> 4;

    const size_t a_off = ((size_t)(b * T_TOT + t0 + l15)) * D_H + 8 * lg4;
    const short8 ah0 = *(const short8*)(q_hi + a_off);
    const short8 ah1 = *(const short8*)(q_hi + a_off + 32);
    const short8 al0 = *(const short8*)(q_lo + a_off);
    const short8 al1 = *(const short8*)(q_lo + a_off + 32);

    const u16* kh = k_hi + (size_t)b * (T_TOT * D_H);
    const u16* kl = k_lo + (size_t)b * (T_TOT * D_H);
    const float* lbase = lint + (size_t)b * T_TOT * T_TOT;

    const int w_lo  = scn * FCH0 + wid * 64;
    const int w_end = min(w_lo + 64, t_max + 1);   // 16-aligned

    float m[4]   = {-3.0e38f, -3.0e38f, -3.0e38f, -3.0e38f};
    float den[4] = {0.f, 0.f, 0.f, 0.f};
    f32x4 oacc[4] = {};
    float tot[4];
    #pragma unroll
    for (int r = 0; r < 4; ++r)
        tot[r] = totalv[b * T_TOT + t0 + 4 * lg4 + r];

    for (int s32 = w_lo; s32 < w_end; s32 += 32) {
        float sc[2][4];
        #pragma unroll
        for (int hh = 0; hh < 2; ++hh) {
            const int sb = s32 + 16 * hh;
            if (sb < w_end) {
                const size_t b_off = ((size_t)(sb + l15)) * D_H + 8 * lg4;
                short8 bh0 = *(const short8*)(kh + b_off);
                short8 bh1 = *(const short8*)(kh + b_off + 32);
                short8 bl0 = *(const short8*)(kl + b_off);
                short8 bl1 = *(const short8*)(kl + b_off + 32);
                f32x4 acc = {0.f, 0.f, 0.f, 0.f};
                acc = __builtin_amdgcn_mfma_f32_16x16x32_bf16(al0, bh0, acc, 0, 0, 0);
                acc = __builtin_amdgcn_mfma_f32_16x16x32_bf16(al1, bh1, acc, 0, 0, 0);
                acc = __builtin_amdgcn_mfma_f32_16x16x32_bf16(ah0, bl0, acc, 0, 0, 0);
                acc = __builtin_amdgcn_mfma_f32_16x16x32_bf16(ah1, bl1, acc, 0, 0, 0);
                acc = __builtin_amdgcn_mfma_f32_16x16x32_bf16(ah0, bh0, acc, 0, 0, 0);
                acc = __builtin_amdgcn_mfma_f32_16x16x32_bf16(ah1, bh1, acc, 0, 0, 0);
                const int c16 = sb >> 4;
                #pragma unroll
                for (int r = 0; r < 4; ++r) {
                    const int tl = 4 * lg4 + r;
                    const int t = t0 + tl;
                    float g = 1.f / (1.f + __expf(-acc[r]));
                    float cs = g;
                    { float n = __shfl_up(cs, 1, 16); if (l15 >= 1) cs += n; }
                    { float n = __shfl_up(cs, 2, 16); if (l15 >= 2) cs += n; }
                    { float n = __shfl_up(cs, 4, 16); if (l15 >= 4) cs += n; }
                    { float n = __shfl_up(cs, 8, 16); if (l15 >= 8) cs += n; }
                    const float base = csumP[((size_t)(b * T_TOT + t)) * NT16 + c16];
                    float pos = tot[r] - (base + cs - g);
                    pos = fminf(fmaxf(pos, 0.f), (float)(T_TOT - 1));
                    const float pf = floorf(pos);
                    const int fi = (int)pf;
                    const int ci = (int)ceilf(pos);
                    const float w = pos - pf;
                    const float* lr = lbase + (size_t)t * T_TOT;
                    const float bias = lr[ci] * w + lr[fi] * (1.f - w);
                    const bool valid = (sb + l15) <= t;
                    sc[hh][r] = valid ? (acc[r] * SCALE + bias) : -3.0e38f;
                }
            } else {
                #pragma unroll
                for (int r = 0; r < 4; ++r) sc[hh][r] = -3.0e38f;
            }
        }
        #pragma unroll
        for (int r = 0; r < 4; ++r) {
            const int tl = 4 * lg4 + r;
            float tmx = fmaxf(sc[0][r], sc[1][r]);
            tmx = fmaxf(tmx, __shfl_xor(tmx, 1));
            tmx = fmaxf(tmx, __shfl_xor(tmx, 2));
            tmx = fmaxf(tmx, __shfl_xor(tmx, 4));
            tmx = fmaxf(tmx, __shfl_xor(tmx, 8));
            const float mn = fmaxf(m[r], tmx);
            const float scl = __expf(m[r] - mn);
            m[r] = mn;
            const float p0 = sc[0][r] > -1.0e37f ? __expf(sc[0][r] - mn) : 0.f;
            const float p1 = sc[1][r] > -1.0e37f ? __expf(sc[1][r] - mn) : 0.f;
            float ps = p0 + p1;
            ps += __shfl_xor(ps, 1); ps += __shfl_xor(ps, 2);
            ps += __shfl_xor(ps, 4); ps += __shfl_xor(ps, 8);
            den[r] = den[r] * scl + ps;
            #pragma unroll
            for (int j = 0; j < 4; ++j) oacc[j][r] *= scl;
            pstage[wid][tl][l15] = f2bf(p0);
            pstage[wid][tl][16 + l15] = f2bf(p1);
        }
        const short8 pa = *(const short8*)&pstage[wid][l15][8 * lg4];
        #pragma unroll
        for (int j = 0; j < 4; ++j) {
            const size_t v_off = ((size_t)(b * D_H + j * 16 + l15)) * T_TOT + s32 + 8 * lg4;
            short8 bv = *(const short8*)(vT + v_off);
            oacc[j] = __builtin_amdgcn_mfma_f32_16x16x32_bf16(pa, bv, oacc[j], 0, 0, 0);
        }
    }

    const size_t pidx = ((size_t)(b * NTBLK + bx)) * NPART + scn * 4 + wid;
    if (l15 == 0) {
        #pragma unroll
        for (int r = 0; r < 4; ++r) {
            fM[pidx * TB + 4 * lg4 + r] = m[r];
            fD[pidx * TB + 4 * lg4 + r] = den[r];
        }
    }
    #pragma unroll
    for (int j = 0; j < 4; ++j)
        #pragma unroll
        for (int r = 0; r < 4; ++r)
            fO[pidx * (TB * D_H) + (size_t)(4 * lg4 + r) * D_H + j * 16 + l15] = oacc[j][r];
}

// ---------------------------------------------------------------------------
// k_fattn1s: iter-1 plain causal flash, same geometry (grid 144 x 9 x 2).
// ---------------------------------------------------------------------------
__global__ __launch_bounds__(256) void k_fattn1s(
    const u16* __restrict__ q_hi, const u16* __restrict__ k_hi,
    const u16* __restrict__ vT,
    float* __restrict__ fM, float* __restrict__ fD, float* __restrict__ fO)
{
    __shared__ u16 pstage[4][TB][32];

    const int b   = blockIdx.z;
    const int scn = blockIdx.y;
    const int bx  = blockIdx.x;
    const int t0 = bx * TB;
    const int t_max = t0 + TB - 1;
    if (scn * FCH0 > t_max) return;

    const int tid = threadIdx.x;
    const int wid = tid >> 6;
    const int lane = tid & 63;
    const int l15 = lane & 15, lg4 = lane >> 4;

    const size_t a_off = ((size_t)(b * T_TOT + t0 + l15)) * D_H + 8 * lg4;
    const short8 ah0 = *(const short8*)(q_hi + a_off);
    const short8 ah1 = *(const short8*)(q_hi + a_off + 32);
    const u16* kh = k_hi + (size_t)b * (T_TOT * D_H);

    const int w_lo  = scn * FCH0 + wid * 64;
    const int w_end = min(w_lo + 64, t_max + 1);

    float m[4]   = {-3.0e38f, -3.0e38f, -3.0e38f, -3.0e38f};
    float den[4] = {0.f, 0.f, 0.f, 0.f};
    f32x4 oacc[4] = {};

    for (int s32 = w_lo; s32 < w_end; s32 += 32) {
        float sc[2][4];
        #pragma unroll
        for (int hh = 0; hh < 2; ++hh) {
            const int sb = s32 + 16 * hh;
            if (sb < w_end) {
                const size_t b_off = ((size_t)(sb + l15)) * D_H + 8 * lg4;
                short8 b0 = *(const short8*)(kh + b_off);
                short8 b1 = *(const short8*)(kh + b_off + 32);
                f32x4 acc = {0.f, 0.f, 0.f, 0.f};
                acc = __builtin_amdgcn_mfma_f32_16x16x32_bf16(ah0, b0, acc, 0, 0, 0);
                acc = __builtin_amdgcn_mfma_f32_16x16x32_bf16(ah1, b1, acc, 0, 0, 0);
                #pragma unroll
                for (int r = 0; r < 4; ++r) {
                    const bool valid = (sb + l15) <= (t0 + 4 * lg4 + r);
                    sc[hh][r] = valid ? acc[r] * SCALE : -3.0e38f;
                }
            } else {
                #pragma unroll
                for (int r = 0; r < 4; ++r) sc[hh][r] = -3.0e38f;
            }
        }
        #pragma unroll
        for (int r = 0; r < 4; ++r) {
            const int tl = 4 * lg4 + r;
            float tmx = fmaxf(sc[0][r], sc[1][r]);
            tmx = fmaxf(tmx, __shfl_xor(tmx, 1));
            tmx = fmaxf(tmx, __shfl_xor(tmx, 2));
            tmx = fmaxf(tmx, __shfl_xor(tmx, 4));
            tmx = fmaxf(tmx, __shfl_xor(tmx, 8));
            const float mn = fmaxf(m[r], tmx);
            const float scl = __expf(m[r] - mn);
            m[r] = mn;
            const float p0 = sc[0][r] > -1.0e37f ? __expf(sc[0][r] - mn) : 0.f;
            const float p1 = sc[1][r] > -1.0e37f ? __expf(sc[1][r] - mn) : 0.f;
            float ps = p0 + p1;
            ps += __shfl_xor(ps, 1); ps += __shfl_xor(ps, 2);
            ps += __shfl_xor(ps, 4); ps += __shfl_xor(ps, 8);
            den[r] = den[r] * scl + ps;
            #pragma unroll
            for (int j = 0; j < 4; ++j) oacc[j][r] *= scl;
            pstage[wid][tl][l15] = f2bf(p0);
            pstage[wid][tl][16 + l15] = f2bf(p1);
        }
        const short8 pa = *(const short8*)&pstage[wid][l15][8 * lg4];
        #pragma unroll
        for (int j = 0; j < 4; ++j) {
            const size_t v_off = ((size_t)(b * D_H + j * 16 + l15)) * T_TOT + s32 + 8 * lg4;
            short8 bv = *(const short8*)(vT + v_off);
            oacc[j] = __builtin_amdgcn_mfma_f32_16x16x32_bf16(pa, bv, oacc[j], 0, 0, 0);
        }
    }

    const size_t pidx = ((size_t)(b * NTBLK + bx)) * NPART + scn * 4 + wid;
    if (l15 == 0) {
        #pragma unroll
        for (int r = 0; r < 4; ++r) {
            fM[pidx * TB + 4 * lg4 + r] = m[r];
            fD[pidx * TB + 4 * lg4 + r] = den[r];
        }
    }
    #pragma unroll
    for (int j = 0; j < 4; ++j)
        #pragma unroll
        for (int r = 0; r < 4; ++r)
            fO[pidx * (TB * D_H) + (size_t)(4 * lg4 + r) * D_H + j * 16 + l15] = oacc[j][r];
}

// ---------------------------------------------------------------------------
// k_fmerge: combine NPART partials per t-block.
// ---------------------------------------------------------------------------
__global__ __launch_bounds__(256) void k_fmerge(
    const float* __restrict__ fM, const float* __restrict__ fD,
    const float* __restrict__ fO, float* __restrict__ outp)
{
    const int bid = blockIdx.x;
    const int b = bid / NTBLK, bx = bid % NTBLK;
    const int t0 = bx * 16, t_max = t0 + 15;
    const int tid = threadIdx.x;
    const int tl = tid >> 4, j4 = (tid & 15) * 4;
    const size_t pb = (size_t)bid * NPART;

    float M = -3.0e38f;
    for (int c = 0; c < NPART; ++c)
        if ((c >> 2) * FCH0 <= t_max) M = fmaxf(M, fM[(pb + c) * TB + tl]);

    float D = 0.f;
    float4 O = {0.f, 0.f, 0.f, 0.f};
    for (int c = 0; c < NPART; ++c) {
        if ((c >> 2) * FCH0 <= t_max) {
            const float w = __expf(fM[(pb + c) * TB + tl] - M);
            D += w * fD[(pb + c) * TB + tl];
            const float4 ov = *(const float4*)&fO[(pb + c) * (TB * D_H) + tl * D_H + j4];
            O.x += w * ov.x; O.y += w * ov.y; O.z += w * ov.z; O.w += w * ov.w;
        }
    }
    const float inv = 1.f / D;
    float4 res; res.x = O.x * inv; res.y = O.y * inv; res.z = O.z * inv; res.w = O.w * inv;
    *(float4*)&outp[((size_t)(b * T_TOT + t0 + tl)) * D_H + j4] = res;
}

// ---------------------------------------------------------------------------
extern "C" void kernel_launch(void* const* d_in, const int* in_sizes, int n_in,
                              void* d_out, int out_size, void* d_ws, size_t ws_size,
                              hipStream_t stream) {
    const float* x    = (const float*)d_in[0];
    const float* Wh   = (const float*)d_in[1];
    const float* Whs  = (const float*)d_in[2];
    const float* Whe  = (const float*)d_in[3];
    const float* Wk   = (const float*)d_in[4];
    const float* Wq   = (const float*)d_in[5];
    const float* Wv   = (const float*)d_in[6];
    const float* Wks  = (const float*)d_in[7];
    const float* Wqs  = (const float*)d_in[8];
    const float* Wvs  = (const float*)d_in[9];
    const float* Wke  = (const float*)d_in[10];
    const float* Wqe  = (const float*)d_in[11];
    const float* Wve  = (const float*)d_in[12];
    const float* ln_g  = (const float*)d_in[13];
    const float* ln_b  = (const float*)d_in[14];
    const float* ln_gs = (const float*)d_in[15];
    const float* ln_bs = (const float*)d_in[16];
    const float* ln_ge = (const float*)d_in[17];
    const float* ln_be = (const float*)d_in[18];
    const float* cope  = (const float*)d_in[19];

    float* out = (float*)d_out;

    const size_t N = (size_t)NROW * D_H;        // 294912
    char* W = (char*)d_ws;
    u16* xn_hi  = (u16*)W;    W += (size_t)NROW * D_IN * 2;
    u16* xn_lo  = (u16*)W;    W += (size_t)NROW * D_IN * 2;
    u16* wT_hi  = (u16*)W;    W += (size_t)3 * D_H * D_IN * 2;
    u16* wT_lo  = (u16*)W;    W += (size_t)3 * D_H * D_IN * 2;
    float* h    = (float*)W;  W += N * 4;
    u16* q_hi   = (u16*)W;    W += N * 2;
    u16* q_lo   = (u16*)W;    W += N * 2;
    u16* k_hi   = (u16*)W;    W += N * 2;
    u16* k_lo   = (u16*)W;    W += N * 2;
    u16* vT     = (u16*)W;    W += N * 2;
    u16* cT_hi  = (u16*)W;    W += (size_t)T_TOT * D_H * 2;
    u16* cT_lo  = (u16*)W;    W += (size_t)T_TOT * D_H * 2;
    float* lint   = (float*)W; W += (size_t)BATCH * T_TOT * T_TOT * 4;   // 42.5MB
    float* csum   = (float*)W; W += (size_t)NROW * NT16 * 4;
    float* csumP  = (float*)W; W += (size_t)NROW * NT16 * 4;
    float* totalv = (float*)W; W += (size_t)NROW * 4;
    float* fM     = (float*)W; W += (size_t)BATCH * NTBLK * NPART * TB * 4;
    float* fD     = (float*)W; W += (size_t)BATCH * NTBLK * NPART * TB * 4;
    float* fO     = (float*)W; W += (size_t)BATCH * NTBLK * NPART * TB * D_H * 4;
    float* mem1   = (float*)W; W += N * 4;

    float* h_part = lint;   // reused before lint is written (8 * N floats)

    k_ln<<<NROW, 256, 0, stream>>>(x, ln_g, ln_b, ln_gs, ln_bs, ln_ge, ln_be,
                                   xn_hi, xn_lo);
    k_prep<<<(WPREP_N + T_TOT * D_H + 255) / 256, 256, 0, stream>>>(
        Wh, Whs, Whe, cope, wT_hi, wT_lo, cT_hi, cT_lo);
    k_hgemm<<<dim3(NROW / 64, KCHUNKS), 256, 0, stream>>>(xn_hi, xn_lo, wT_hi, wT_lo, h_part);
    k_hred<<<(int)(N / 256), 256, 0, stream>>>(h_part, h);

    // iteration 0 (CoPE)
    k_qkv<true><<<NROW, 192, 0, stream>>>(h, Wk, Wq, Wv, Wks, Wqs, Wvs, Wke, Wqe, Wve,
                                          q_hi, q_lo, k_hi, k_lo, vT);
    k_lint<<<dim3(T_TOT / 64, T_TOT / 64, BATCH), 256, 0, stream>>>(
        q_hi, q_lo, cT_hi, cT_lo, lint);
    k_gates<<<dim3(T_TOT / 64, T_TOT / 64, BATCH), 256, 0, stream>>>(
        q_hi, q_lo, k_hi, k_lo, csum);
    k_cscan<<<NROW / 256, 256, 0, stream>>>(csum, csumP, totalv);
    k_fattn0<<<dim3(NTBLK, NSC0, BATCH), 256, 0, stream>>>(
        q_hi, q_lo, k_hi, k_lo, vT, lint, csumP, totalv, fM, fD, fO);
    k_fmerge<<<BATCH * NTBLK, 256, 0, stream>>>(fM, fD, fO, mem1);

    // iteration 1 (plain causal)
    k_qkv<false><<<NROW, 192, 0, stream>>>(mem1, Wk, Wq, Wv, Wks, Wqs, Wvs, Wke, Wqe, Wve,
                                           q_hi, q_lo, k_hi, k_lo, vT);
    k_fattn1s<<<dim3(NTBLK, NSC0, BATCH), 256, 0, stream>>>(q_hi, k_hi, vT, fM, fD, fO);
    k_fmerge<<<BATCH * NTBLK, 256, 0, stream>>>(fM, fD, fO, out);
}

// Round 10
// 193.228 us; speedup vs baseline: 1.1886x; 1.1886x over previous
//
#include <hip/hip_runtime.h>

#define T_TOT 2304
#define S_LEN 128
#define D_IN  1024
#define D_H   64
#define BATCH 2
#define NROW  (BATCH * T_TOT)
#define SCALE 0.125f
#define KCHUNKS 8
#define KCW   (D_IN / KCHUNKS)   // 128
#define TB    16                 // t-rows per flash block
#define FCH0  768                // s-chunk width
#define NSC0  3                  // number of s-chunks
#define WSPAN (FCH0 / 4)         // 192 cols per wave
#define NTBLK (T_TOT / TB)       // 144
#define NT16  (T_TOT / 16)       // 144 col-tiles
#define NPART (NSC0 * 4)         // 12 partials per t-block

typedef unsigned short u16;
typedef __attribute__((ext_vector_type(8))) short short8;
typedef __attribute__((ext_vector_type(4))) float f32x4;
typedef __attribute__((ext_vector_type(4))) unsigned short u16x4;

static __device__ __forceinline__ u16 f2bf(float f) {
    unsigned u = __float_as_uint(f);
    unsigned r = (u + 0x7fffu + ((u >> 16) & 1u)) >> 16;
    return (u16)r;
}
static __device__ __forceinline__ float bf2f(u16 s) {
    return __uint_as_float((unsigned)s << 16);
}

// ---------------------------------------------------------------------------
// Kernel 1a: LayerNorm(x_row) -> xn hi/lo (split bf16). One block (256)/row.
// ---------------------------------------------------------------------------
__global__ __launch_bounds__(256) void k_ln(
    const float* __restrict__ x,
    const float* __restrict__ ln_g,  const float* __restrict__ ln_b,
    const float* __restrict__ ln_gs, const float* __restrict__ ln_bs,
    const float* __restrict__ ln_ge, const float* __restrict__ ln_be,
    u16* __restrict__ xn_hi, u16* __restrict__ xn_lo)
{
    __shared__ float red1[256], red2[256];
    const int row = blockIdx.x;
    const int t = row % T_TOT;
    const int tid = threadIdx.x;

    const float *gg, *bb;
    if (t < S_LEN)               { gg = ln_gs; bb = ln_bs; }
    else if (t >= T_TOT - S_LEN) { gg = ln_ge; bb = ln_be; }
    else                         { gg = ln_g;  bb = ln_b;  }

    const float4 xv = *(const float4*)(x + (size_t)row * D_IN + 4 * tid);
    float s  = xv.x + xv.y + xv.z + xv.w;
    float s2 = xv.x * xv.x + xv.y * xv.y + xv.z * xv.z + xv.w * xv.w;
    red1[tid] = s; red2[tid] = s2; __syncthreads();
    for (int off = 128; off > 0; off >>= 1) {
        if (tid < off) { red1[tid] += red1[tid + off]; red2[tid] += red2[tid + off]; }
        __syncthreads();
    }
    const float mean = red1[0] * (1.f / D_IN);
    const float var  = red2[0] * (1.f / D_IN) - mean * mean;
    const float rstd = rsqrtf(var + 1e-5f);

    const float4 gv = *(const float4*)(gg + 4 * tid);
    const float4 bv = *(const float4*)(bb + 4 * tid);
    float o0 = (xv.x - mean) * rstd * gv.x + bv.x;
    float o1 = (xv.y - mean) * rstd * gv.y + bv.y;
    float o2 = (xv.z - mean) * rstd * gv.z + bv.z;
    float o3 = (xv.w - mean) * rstd * gv.w + bv.w;

    u16x4 hv, lv;
    hv[0] = f2bf(o0); lv[0] = f2bf(o0 - bf2f(hv[0]));
    hv[1] = f2bf(o1); lv[1] = f2bf(o1 - bf2f(hv[1]));
    hv[2] = f2bf(o2); lv[2] = f2bf(o2 - bf2f(hv[2]));
    hv[3] = f2bf(o3); lv[3] = f2bf(o3 - bf2f(hv[3]));
    *(u16x4*)(xn_hi + (size_t)row * D_IN + 4 * tid) = hv;
    *(u16x4*)(xn_lo + (size_t)row * D_IN + 4 * tid) = lv;
}

// ---------------------------------------------------------------------------
// Kernel 1b: prep — transpose+split Wh/Whs/Whe, and split cope_emb^T
// ---------------------------------------------------------------------------
#define WPREP_N (3 * D_H * D_IN)
__global__ __launch_bounds__(256) void k_prep(
    const float* __restrict__ Wh, const float* __restrict__ Whs, const float* __restrict__ Whe,
    const float* __restrict__ cope,
    u16* __restrict__ wT_hi, u16* __restrict__ wT_lo,
    u16* __restrict__ cT_hi, u16* __restrict__ cT_lo)
{
    const int gid = blockIdx.x * 256 + threadIdx.x;
    if (gid < WPREP_N) {
        const int seg = gid >> 16;
        const int o = gid & 65535;
        const int j = o >> 10, k = o & 1023;
        const float* W = seg == 0 ? Wh : (seg == 1 ? Whs : Whe);
        const float f = W[k * D_H + j];
        const u16 hi = f2bf(f);
        wT_hi[gid] = hi;
        wT_lo[gid] = f2bf(f - bf2f(hi));
    } else {
        const int idx = gid - WPREP_N;
        if (idx < T_TOT * D_H) {
            const int n = idx >> 6, d = idx & 63;
            const float f = cope[(size_t)d * T_TOT + n];
            const u16 hi = f2bf(f);
            cT_hi[idx] = hi;
            cT_lo[idx] = f2bf(f - bf2f(hi));
        }
    }
}

// ---------------------------------------------------------------------------
// Kernel 1c: h_part[kc] = LN(x)[:, kc*128:+128] @ W_seg[kc chunk]  (MFMA, split)
// ---------------------------------------------------------------------------
__global__ __launch_bounds__(256) void k_hgemm(
    const u16* __restrict__ xn_hi, const u16* __restrict__ xn_lo,
    const u16* __restrict__ wT_hi, const u16* __restrict__ wT_lo,
    float* __restrict__ h_part)
{
    const int tile = blockIdx.x;              // 0..71
    const int kc   = blockIdx.y;              // 0..7
    const int k0   = kc * KCW;
    const int tt = tile % 36;
    const int seg = tt < 2 ? 1 : (tt >= 34 ? 2 : 0);

    __shared__ u16 Bh[64 * KCW];
    __shared__ u16 Bl[64 * KCW];

    const int tid = threadIdx.x;
    {
        const int r = tid >> 2;
        const int c0 = (tid & 3) * 32;
        const u16* sh = wT_hi + ((size_t)seg * D_H + r) * D_IN + k0 + c0;
        const u16* sl = wT_lo + ((size_t)seg * D_H + r) * D_IN + k0 + c0;
        const int sw = (r & 7) << 3;
        #pragma unroll
        for (int u = 0; u < 4; ++u) {
            const int col = c0 + 8 * u;
            *(short8*)&Bh[r * KCW + (col ^ sw)] = *(const short8*)(sh + 8 * u);
            *(short8*)&Bl[r * KCW + (col ^ sw)] = *(const short8*)(sl + 8 * u);
        }
    }
    __syncthreads();

    const int w = tid >> 6;
    const int lane = tid & 63;
    const int l15 = lane & 15, lg4 = lane >> 4;
    const int row0 = tile * 64 + w * 16;

    const size_t abase = (size_t)(row0 + l15) * D_IN + k0 + 8 * lg4;
    f32x4 acc[4] = {};

    #pragma unroll
    for (int kk = 0; kk < KCW / 32; ++kk) {
        short8 ah = *(const short8*)(xn_hi + abase + kk * 32);
        short8 al = *(const short8*)(xn_lo + abase + kk * 32);
        #pragma unroll
        for (int j = 0; j < 4; ++j) {
            const int brow = j * 16 + l15;
            const int col = (kk * 32 + 8 * lg4) ^ ((brow & 7) << 3);
            short8 bh = *(const short8*)&Bh[brow * KCW + col];
            short8 bl = *(const short8*)&Bl[brow * KCW + col];
            acc[j] = __builtin_amdgcn_mfma_f32_16x16x32_bf16(al, bh, acc[j], 0, 0, 0);
            acc[j] = __builtin_amdgcn_mfma_f32_16x16x32_bf16(ah, bl, acc[j], 0, 0, 0);
            acc[j] = __builtin_amdgcn_mfma_f32_16x16x32_bf16(ah, bh, acc[j], 0, 0, 0);
        }
    }
    float* hp = h_part + (size_t)kc * ((size_t)NROW * D_H);
    #pragma unroll
    for (int j = 0; j < 4; ++j)
        #pragma unroll
        for (int r = 0; r < 4; ++r)
            hp[(size_t)(row0 + 4 * lg4 + r) * D_H + j * 16 + l15] = acc[j][r];
}

// ---------------------------------------------------------------------------
// Kernel 1d: h = sum_kc h_part[kc]
// ---------------------------------------------------------------------------
__global__ __launch_bounds__(256) void k_hred(
    const float* __restrict__ h_part, float* __restrict__ h)
{
    const size_t idx = (size_t)blockIdx.x * 256 + threadIdx.x;
    const size_t N = (size_t)NROW * D_H;
    float s = 0.f;
    #pragma unroll
    for (int kc = 0; kc < KCHUNKS; ++kc) s += h_part[kc * N + idx];
    h[idx] = s;
}

// ---------------------------------------------------------------------------
// Kernel 2: q/k/v projections.
// ---------------------------------------------------------------------------
template <bool SPLIT>
__global__ __launch_bounds__(192) void k_qkv(
    const float* __restrict__ hin,
    const float* __restrict__ Wk,  const float* __restrict__ Wq,  const float* __restrict__ Wv,
    const float* __restrict__ Wks, const float* __restrict__ Wqs, const float* __restrict__ Wvs,
    const float* __restrict__ Wke, const float* __restrict__ Wqe, const float* __restrict__ Wve,
    u16* __restrict__ q_hi, u16* __restrict__ q_lo,
    u16* __restrict__ k_hi, u16* __restrict__ k_lo,
    u16* __restrict__ vT)
{
    __shared__ float hr[D_H];
    const int bid = blockIdx.x;
    const int b = bid / T_TOT, t = bid % T_TOT;
    const int tid = threadIdx.x;

    const float* hrow = hin + ((size_t)b * T_TOT + t) * D_H;
    if (tid < D_H) hr[tid] = hrow[tid];
    __syncthreads();

    const int which = tid >> 6, j = tid & 63;
    const float* W;
    if (t < S_LEN)               W = which == 0 ? Wks : (which == 1 ? Wqs : Wvs);
    else if (t >= T_TOT - S_LEN) W = which == 0 ? Wke : (which == 1 ? Wqe : Wve);
    else                         W = which == 0 ? Wk  : (which == 1 ? Wq  : Wv);

    float acc = 0.f;
    #pragma unroll
    for (int d = 0; d < D_H; ++d) acc += hr[d] * W[d * D_H + j];

    const size_t idx = ((size_t)b * T_TOT + t) * D_H + j;
    u16 hi = f2bf(acc);
    if (which == 0) {
        k_hi[idx] = hi;
        if (SPLIT) k_lo[idx] = f2bf(acc - bf2f(hi));
    } else if (which == 1) {
        q_hi[idx] = hi;
        if (SPLIT) q_lo[idx] = f2bf(acc - bf2f(hi));
    } else {
        vT[((size_t)b * D_H + j) * T_TOT + t] = hi;
    }
}

// ---------------------------------------------------------------------------
// k_lg: fused gates + lint. Pass 0: dense QK^T -> per-16-tile sigmoid sums.
// Pass 1: lint = q . cope^T (written fp32). A-fragments loaded once.
// Grid (36, 36, 2); wave 16t x 64s.
// ---------------------------------------------------------------------------
__global__ __launch_bounds__(256) void k_lg(
    const u16* __restrict__ a_hi, const u16* __restrict__ a_lo,
    const u16* __restrict__ k_hi, const u16* __restrict__ k_lo,
    const u16* __restrict__ c_hi, const u16* __restrict__ c_lo,
    float* __restrict__ lint, float* __restrict__ csum)
{
    const int b  = blockIdx.z;
    const int s0 = blockIdx.x * 64;
    const int t0 = blockIdx.y * 64 + (threadIdx.x >> 6) * 16;
    const int lane = threadIdx.x & 63;
    const int l15 = lane & 15, lg4 = lane >> 4;

    const size_t a_off = ((size_t)(b * T_TOT + t0 + l15)) * D_H + 8 * lg4;
    const short8 ah0 = *(const short8*)(a_hi + a_off);
    const short8 ah1 = *(const short8*)(a_hi + a_off + 32);
    const short8 al0 = *(const short8*)(a_lo + a_off);
    const short8 al1 = *(const short8*)(a_lo + a_off + 32);

    // ---- pass 0: gates -> csum ----
    {
        const u16* bh = k_hi + (size_t)b * (T_TOT * D_H);
        const u16* bl = k_lo + (size_t)b * (T_TOT * D_H);
        #pragma unroll
        for (int ni = 0; ni < 4; ++ni) {
            const size_t b_off = ((size_t)(s0 + ni * 16 + l15)) * D_H + 8 * lg4;
            short8 bh0 = *(const short8*)(bh + b_off);
            short8 bh1 = *(const short8*)(bh + b_off + 32);
            short8 bl0 = *(const short8*)(bl + b_off);
            short8 bl1 = *(const short8*)(bl + b_off + 32);
            f32x4 acc = {0.f, 0.f, 0.f, 0.f};
            acc = __builtin_amdgcn_mfma_f32_16x16x32_bf16(al0, bh0, acc, 0, 0, 0);
            acc = __builtin_amdgcn_mfma_f32_16x16x32_bf16(al1, bh1, acc, 0, 0, 0);
            acc = __builtin_amdgcn_mfma_f32_16x16x32_bf16(ah0, bl0, acc, 0, 0, 0);
            acc = __builtin_amdgcn_mfma_f32_16x16x32_bf16(ah1, bl1, acc, 0, 0, 0);
            acc = __builtin_amdgcn_mfma_f32_16x16x32_bf16(ah0, bh0, acc, 0, 0, 0);
            acc = __builtin_amdgcn_mfma_f32_16x16x32_bf16(ah1, bh1, acc, 0, 0, 0);
            const int c16 = (s0 >> 4) + ni;
            #pragma unroll
            for (int r = 0; r < 4; ++r) {
                float g = 1.f / (1.f + __expf(-acc[r]));
                g += __shfl_xor(g, 1); g += __shfl_xor(g, 2);
                g += __shfl_xor(g, 4); g += __shfl_xor(g, 8);
                if (l15 == 0)
                    csum[((size_t)(b * T_TOT + t0 + 4 * lg4 + r)) * NT16 + c16] = g;
            }
        }
    }

    // ---- pass 1: lint ----
    {
        float* o = lint + ((size_t)(b * T_TOT + t0 + 4 * lg4)) * T_TOT + s0 + l15;
        #pragma unroll
        for (int ni = 0; ni < 4; ++ni) {
            const size_t b_off = ((size_t)(s0 + ni * 16 + l15)) * D_H + 8 * lg4;
            short8 bh0 = *(const short8*)(c_hi + b_off);
            short8 bh1 = *(const short8*)(c_hi + b_off + 32);
            short8 bl0 = *(const short8*)(c_lo + b_off);
            short8 bl1 = *(const short8*)(c_lo + b_off + 32);
            f32x4 acc = {0.f, 0.f, 0.f, 0.f};
            acc = __builtin_amdgcn_mfma_f32_16x16x32_bf16(al0, bh0, acc, 0, 0, 0);
            acc = __builtin_amdgcn_mfma_f32_16x16x32_bf16(al1, bh1, acc, 0, 0, 0);
            acc = __builtin_amdgcn_mfma_f32_16x16x32_bf16(ah0, bl0, acc, 0, 0, 0);
            acc = __builtin_amdgcn_mfma_f32_16x16x32_bf16(ah1, bl1, acc, 0, 0, 0);
            acc = __builtin_amdgcn_mfma_f32_16x16x32_bf16(ah0, bh0, acc, 0, 0, 0);
            acc = __builtin_amdgcn_mfma_f32_16x16x32_bf16(ah1, bh1, acc, 0, 0, 0);
            #pragma unroll
            for (int r = 0; r < 4; ++r)
                o[(size_t)r * T_TOT + ni * 16] = acc[r];
        }
    }
}

// ---------------------------------------------------------------------------
// k_cscan: per-row exclusive prefix of csum tiles + total.
// ---------------------------------------------------------------------------
__global__ __launch_bounds__(256) void k_cscan(
    const float* __restrict__ csum, float* __restrict__ csumP,
    float* __restrict__ totalv)
{
    const int row = blockIdx.x * 256 + threadIdx.x;   // < NROW
    const size_t base = (size_t)row * NT16;
    float run = 0.f;
    for (int c = 0; c < NT16; ++c) {
        csumP[base + c] = run;
        run += csum[base + c];
    }
    totalv[row] = run;
}

// ---------------------------------------------------------------------------
// k_fattn0: iter-0 flash with CoPE. Grid (144, 3, 2); wave span 192 cols.
// Recomputes QK^T tiles (3-term), gates + within-16 scan + csumP base -> pos,
// gathers bias from lint (global), online softmax + PV. Writes {m,d,O}.
// ---------------------------------------------------------------------------
__global__ __launch_bounds__(256) void k_fattn0(
    const u16* __restrict__ q_hi, const u16* __restrict__ q_lo,
    const u16* __restrict__ k_hi, const u16* __restrict__ k_lo,
    const u16* __restrict__ vT,
    const float* __restrict__ lint, const float* __restrict__ csumP,
    const float* __restrict__ totalv,
    float* __restrict__ fM, float* __restrict__ fD, float* __restrict__ fO)
{
    __shared__ u16 pstage[4][TB][40];   // padded row (80B) to kill bank conflicts

    const int b   = blockIdx.z;
    const int scn = blockIdx.y;
    const int bx  = blockIdx.x;
    const int t0 = bx * TB;
    const int t_max = t0 + TB - 1;
    if (scn * FCH0 > t_max) return;

    const int tid = threadIdx.x;
    const int wid = tid >> 6;
    const int lane = tid & 63;
    const int l15 = lane & 15, lg4 = lane >> 4;

    const size_t a_off = ((size_t)(b * T_TOT + t0 + l15)) * D_H + 8 * lg4;
    const short8 ah0 = *(const short8*)(q_hi + a_off);
    const short8 ah1 = *(const short8*)(q_hi + a_off + 32);
    const short8 al0 = *(const short8*)(q_lo + a_off);
    const short8 al1 = *(const short8*)(q_lo + a_off + 32);

    const u16* kh = k_hi + (size_t)b * (T_TOT * D_H);
    const u16* kl = k_lo + (size_t)b * (T_TOT * D_H);
    const float* lbase = lint + (size_t)b * T_TOT * T_TOT;

    const int w_lo  = scn * FCH0 + wid * WSPAN;
    const int w_end = min(w_lo + WSPAN, t_max + 1);   // 16-aligned

    float m[4]   = {-3.0e38f, -3.0e38f, -3.0e38f, -3.0e38f};
    float den[4] = {0.f, 0.f, 0.f, 0.f};
    f32x4 oacc[4] = {};
    float tot[4];
    #pragma unroll
    for (int r = 0; r < 4; ++r)
        tot[r] = totalv[b * T_TOT + t0 + 4 * lg4 + r];

    for (int s32 = w_lo; s32 < w_end; s32 += 32) {
        float sc[2][4];
        #pragma unroll
        for (int hh = 0; hh < 2; ++hh) {
            const int sb = s32 + 16 * hh;
            if (sb < w_end) {
                const size_t b_off = ((size_t)(sb + l15)) * D_H + 8 * lg4;
                short8 bh0 = *(const short8*)(kh + b_off);
                short8 bh1 = *(const short8*)(kh + b_off + 32);
                short8 bl0 = *(const short8*)(kl + b_off);
                short8 bl1 = *(const short8*)(kl + b_off + 32);
                f32x4 acc = {0.f, 0.f, 0.f, 0.f};
                acc = __builtin_amdgcn_mfma_f32_16x16x32_bf16(al0, bh0, acc, 0, 0, 0);
                acc = __builtin_amdgcn_mfma_f32_16x16x32_bf16(al1, bh1, acc, 0, 0, 0);
                acc = __builtin_amdgcn_mfma_f32_16x16x32_bf16(ah0, bl0, acc, 0, 0, 0);
                acc = __builtin_amdgcn_mfma_f32_16x16x32_bf16(ah1, bl1, acc, 0, 0, 0);
                acc = __builtin_amdgcn_mfma_f32_16x16x32_bf16(ah0, bh0, acc, 0, 0, 0);
                acc = __builtin_amdgcn_mfma_f32_16x16x32_bf16(ah1, bh1, acc, 0, 0, 0);
                const int c16 = sb >> 4;
                #pragma unroll
                for (int r = 0; r < 4; ++r) {
                    const int tl = 4 * lg4 + r;
                    const int t = t0 + tl;
                    float g = 1.f / (1.f + __expf(-acc[r]));
                    float cs = g;
                    { float n = __shfl_up(cs, 1, 16); if (l15 >= 1) cs += n; }
                    { float n = __shfl_up(cs, 2, 16); if (l15 >= 2) cs += n; }
                    { float n = __shfl_up(cs, 4, 16); if (l15 >= 4) cs += n; }
                    { float n = __shfl_up(cs, 8, 16); if (l15 >= 8) cs += n; }
                    const float base = csumP[((size_t)(b * T_TOT + t)) * NT16 + c16];
                    float pos = tot[r] - (base + cs - g);
                    pos = fminf(fmaxf(pos, 0.f), (float)(T_TOT - 1));
                    const float pf = floorf(pos);
                    const int fi = (int)pf;
                    const int ci = (int)ceilf(pos);
                    const float w = pos - pf;
                    const float* lr = lbase + (size_t)t * T_TOT;
                    const float bias = lr[ci] * w + lr[fi] * (1.f - w);
                    const bool valid = (sb + l15) <= t;
                    sc[hh][r] = valid ? (acc[r] * SCALE + bias) : -3.0e38f;
                }
            } else {
                #pragma unroll
                for (int r = 0; r < 4; ++r) sc[hh][r] = -3.0e38f;
            }
        }
        #pragma unroll
        for (int r = 0; r < 4; ++r) {
            const int tl = 4 * lg4 + r;
            float tmx = fmaxf(sc[0][r], sc[1][r]);
            tmx = fmaxf(tmx, __shfl_xor(tmx, 1));
            tmx = fmaxf(tmx, __shfl_xor(tmx, 2));
            tmx = fmaxf(tmx, __shfl_xor(tmx, 4));
            tmx = fmaxf(tmx, __shfl_xor(tmx, 8));
            const float mn = fmaxf(m[r], tmx);
            const float scl = __expf(m[r] - mn);
            m[r] = mn;
            const float p0 = sc[0][r] > -1.0e37f ? __expf(sc[0][r] - mn) : 0.f;
            const float p1 = sc[1][r] > -1.0e37f ? __expf(sc[1][r] - mn) : 0.f;
            float ps = p0 + p1;
            ps += __shfl_xor(ps, 1); ps += __shfl_xor(ps, 2);
            ps += __shfl_xor(ps, 4); ps += __shfl_xor(ps, 8);
            den[r] = den[r] * scl + ps;
            #pragma unroll
            for (int j = 0; j < 4; ++j) oacc[j][r] *= scl;
            pstage[wid][tl][l15] = f2bf(p0);
            pstage[wid][tl][16 + l15] = f2bf(p1);
        }
        const short8 pa = *(const short8*)&pstage[wid][l15][8 * lg4];
        #pragma unroll
        for (int j = 0; j < 4; ++j) {
            const size_t v_off = ((size_t)(b * D_H + j * 16 + l15)) * T_TOT + s32 + 8 * lg4;
            short8 bv = *(const short8*)(vT + v_off);
            oacc[j] = __builtin_amdgcn_mfma_f32_16x16x32_bf16(pa, bv, oacc[j], 0, 0, 0);
        }
    }

    const size_t pidx = ((size_t)(b * NTBLK + bx)) * NPART + scn * 4 + wid;
    if (l15 == 0) {
        #pragma unroll
        for (int r = 0; r < 4; ++r) {
            fM[pidx * TB + 4 * lg4 + r] = m[r];
            fD[pidx * TB + 4 * lg4 + r] = den[r];
        }
    }
    #pragma unroll
    for (int j = 0; j < 4; ++j)
        #pragma unroll
        for (int r = 0; r < 4; ++r)
            fO[pidx * (TB * D_H) + (size_t)(4 * lg4 + r) * D_H + j * 16 + l15] = oacc[j][r];
}

// ---------------------------------------------------------------------------
// k_fattn1s: iter-1 plain causal flash, same geometry (grid 144 x 3 x 2).
// ---------------------------------------------------------------------------
__global__ __launch_bounds__(256) void k_fattn1s(
    const u16* __restrict__ q_hi, const u16* __restrict__ k_hi,
    const u16* __restrict__ vT,
    float* __restrict__ fM, float* __restrict__ fD, float* __restrict__ fO)
{
    __shared__ u16 pstage[4][TB][40];

    const int b   = blockIdx.z;
    const int scn = blockIdx.y;
    const int bx  = blockIdx.x;
    const int t0 = bx * TB;
    const int t_max = t0 + TB - 1;
    if (scn * FCH0 > t_max) return;

    const int tid = threadIdx.x;
    const int wid = tid >> 6;
    const int lane = tid & 63;
    const int l15 = lane & 15, lg4 = lane >> 4;

    const size_t a_off = ((size_t)(b * T_TOT + t0 + l15)) * D_H + 8 * lg4;
    const short8 ah0 = *(const short8*)(q_hi + a_off);
    const short8 ah1 = *(const short8*)(q_hi + a_off + 32);
    const u16* kh = k_hi + (size_t)b * (T_TOT * D_H);

    const int w_lo  = scn * FCH0 + wid * WSPAN;
    const int w_end = min(w_lo + WSPAN, t_max + 1);

    float m[4]   = {-3.0e38f, -3.0e38f, -3.0e38f, -3.0e38f};
    float den[4] = {0.f, 0.f, 0.f, 0.f};
    f32x4 oacc[4] = {};

    for (int s32 = w_lo; s32 < w_end; s32 += 32) {
        float sc[2][4];
        #pragma unroll
        for (int hh = 0; hh < 2; ++hh) {
            const int sb = s32 + 16 * hh;
            if (sb < w_end) {
                const size_t b_off = ((size_t)(sb + l15)) * D_H + 8 * lg4;
                short8 b0 = *(const short8*)(kh + b_off);
                short8 b1 = *(const short8*)(kh + b_off + 32);
                f32x4 acc = {0.f, 0.f, 0.f, 0.f};
                acc = __builtin_amdgcn_mfma_f32_16x16x32_bf16(ah0, b0, acc, 0, 0, 0);
                acc = __builtin_amdgcn_mfma_f32_16x16x32_bf16(ah1, b1, acc, 0, 0, 0);
                #pragma unroll
                for (int r = 0; r < 4; ++r) {
                    const bool valid = (sb + l15) <= (t0 + 4 * lg4 + r);
                    sc[hh][r] = valid ? acc[r] * SCALE : -3.0e38f;
                }
            } else {
                #pragma unroll
                for (int r = 0; r < 4; ++r) sc[hh][r] = -3.0e38f;
            }
        }
        #pragma unroll
        for (int r = 0; r < 4; ++r) {
            const int tl = 4 * lg4 + r;
            float tmx = fmaxf(sc[0][r], sc[1][r]);
            tmx = fmaxf(tmx, __shfl_xor(tmx, 1));
            tmx = fmaxf(tmx, __shfl_xor(tmx, 2));
            tmx = fmaxf(tmx, __shfl_xor(tmx, 4));
            tmx = fmaxf(tmx, __shfl_xor(tmx, 8));
            const float mn = fmaxf(m[r], tmx);
            const float scl = __expf(m[r] - mn);
            m[r] = mn;
            const float p0 = sc[0][r] > -1.0e37f ? __expf(sc[0][r] - mn) : 0.f;
            const float p1 = sc[1][r] > -1.0e37f ? __expf(sc[1][r] - mn) : 0.f;
            float ps = p0 + p1;
            ps += __shfl_xor(ps, 1); ps += __shfl_xor(ps, 2);
            ps += __shfl_xor(ps, 4); ps += __shfl_xor(ps, 8);
            den[r] = den[r] * scl + ps;
            #pragma unroll
            for (int j = 0; j < 4; ++j) oacc[j][r] *= scl;
            pstage[wid][tl][l15] = f2bf(p0);
            pstage[wid][tl][16 + l15] = f2bf(p1);
        }
        const short8 pa = *(const short8*)&pstage[wid][l15][8 * lg4];
        #pragma unroll
        for (int j = 0; j < 4; ++j) {
            const size_t v_off = ((size_t)(b * D_H + j * 16 + l15)) * T_TOT + s32 + 8 * lg4;
            short8 bv = *(const short8*)(vT + v_off);
            oacc[j] = __builtin_amdgcn_mfma_f32_16x16x32_bf16(pa, bv, oacc[j], 0, 0, 0);
        }
    }

    const size_t pidx = ((size_t)(b * NTBLK + bx)) * NPART + scn * 4 + wid;
    if (l15 == 0) {
        #pragma unroll
        for (int r = 0; r < 4; ++r) {
            fM[pidx * TB + 4 * lg4 + r] = m[r];
            fD[pidx * TB + 4 * lg4 + r] = den[r];
        }
    }
    #pragma unroll
    for (int j = 0; j < 4; ++j)
        #pragma unroll
        for (int r = 0; r < 4; ++r)
            fO[pidx * (TB * D_H) + (size_t)(4 * lg4 + r) * D_H + j * 16 + l15] = oacc[j][r];
}

// ---------------------------------------------------------------------------
// k_fmerge: combine NPART partials per t-block.
// ---------------------------------------------------------------------------
__global__ __launch_bounds__(256) void k_fmerge(
    const float* __restrict__ fM, const float* __restrict__ fD,
    const float* __restrict__ fO, float* __restrict__ outp)
{
    const int bid = blockIdx.x;
    const int b = bid / NTBLK, bx = bid % NTBLK;
    const int t0 = bx * 16, t_max = t0 + 15;
    const int tid = threadIdx.x;
    const int tl = tid >> 4, j4 = (tid & 15) * 4;
    const size_t pb = (size_t)bid * NPART;

    float M = -3.0e38f;
    for (int c = 0; c < NPART; ++c)
        if ((c >> 2) * FCH0 <= t_max) M = fmaxf(M, fM[(pb + c) * TB + tl]);

    float D = 0.f;
    float4 O = {0.f, 0.f, 0.f, 0.f};
    for (int c = 0; c < NPART; ++c) {
        if ((c >> 2) * FCH0 <= t_max) {
            const float w = __expf(fM[(pb + c) * TB + tl] - M);
            D += w * fD[(pb + c) * TB + tl];
            const float4 ov = *(const float4*)&fO[(pb + c) * (TB * D_H) + tl * D_H + j4];
            O.x += w * ov.x; O.y += w * ov.y; O.z += w * ov.z; O.w += w * ov.w;
        }
    }
    const float inv = 1.f / D;
    float4 res; res.x = O.x * inv; res.y = O.y * inv; res.z = O.z * inv; res.w = O.w * inv;
    *(float4*)&outp[((size_t)(b * T_TOT + t0 + tl)) * D_H + j4] = res;
}

// ---------------------------------------------------------------------------
extern "C" void kernel_launch(void* const* d_in, const int* in_sizes, int n_in,
                              void* d_out, int out_size, void* d_ws, size_t ws_size,
                              hipStream_t stream) {
    const float* x    = (const float*)d_in[0];
    const float* Wh   = (const float*)d_in[1];
    const float* Whs  = (const float*)d_in[2];
    const float* Whe  = (const float*)d_in[3];
    const float* Wk   = (const float*)d_in[4];
    const float* Wq   = (const float*)d_in[5];
    const float* Wv   = (const float*)d_in[6];
    const float* Wks  = (const float*)d_in[7];
    const float* Wqs  = (const float*)d_in[8];
    const float* Wvs  = (const float*)d_in[9];
    const float* Wke  = (const float*)d_in[10];
    const float* Wqe  = (const float*)d_in[11];
    const float* Wve  = (const float*)d_in[12];
    const float* ln_g  = (const float*)d_in[13];
    const float* ln_b  = (const float*)d_in[14];
    const float* ln_gs = (const float*)d_in[15];
    const float* ln_bs = (const float*)d_in[16];
    const float* ln_ge = (const float*)d_in[17];
    const float* ln_be = (const float*)d_in[18];
    const float* cope  = (const float*)d_in[19];

    float* out = (float*)d_out;

    const size_t N = (size_t)NROW * D_H;        // 294912
    char* W = (char*)d_ws;
    u16* xn_hi  = (u16*)W;    W += (size_t)NROW * D_IN * 2;
    u16* xn_lo  = (u16*)W;    W += (size_t)NROW * D_IN * 2;
    u16* wT_hi  = (u16*)W;    W += (size_t)3 * D_H * D_IN * 2;
    u16* wT_lo  = (u16*)W;    W += (size_t)3 * D_H * D_IN * 2;
    float* h    = (float*)W;  W += N * 4;
    u16* q_hi   = (u16*)W;    W += N * 2;
    u16* q_lo   = (u16*)W;    W += N * 2;
    u16* k_hi   = (u16*)W;    W += N * 2;
    u16* k_lo   = (u16*)W;    W += N * 2;
    u16* vT     = (u16*)W;    W += N * 2;
    u16* cT_hi  = (u16*)W;    W += (size_t)T_TOT * D_H * 2;
    u16* cT_lo  = (u16*)W;    W += (size_t)T_TOT * D_H * 2;
    float* lint   = (float*)W; W += (size_t)BATCH * T_TOT * T_TOT * 4;   // 42.5MB
    float* csum   = (float*)W; W += (size_t)NROW * NT16 * 4;
    float* csumP  = (float*)W; W += (size_t)NROW * NT16 * 4;
    float* totalv = (float*)W; W += (size_t)NROW * 4;
    float* fM     = (float*)W; W += (size_t)BATCH * NTBLK * NPART * TB * 4;
    float* fD     = (float*)W; W += (size_t)BATCH * NTBLK * NPART * TB * 4;
    float* fO     = (float*)W; W += (size_t)BATCH * NTBLK * NPART * TB * D_H * 4;
    float* mem1   = (float*)W; W += N * 4;

    float* h_part = lint;   // reused before lint is written (8 * N floats)

    k_ln<<<NROW, 256, 0, stream>>>(x, ln_g, ln_b, ln_gs, ln_bs, ln_ge, ln_be,
                                   xn_hi, xn_lo);
    k_prep<<<(WPREP_N + T_TOT * D_H + 255) / 256, 256, 0, stream>>>(
        Wh, Whs, Whe, cope, wT_hi, wT_lo, cT_hi, cT_lo);
    k_hgemm<<<dim3(NROW / 64, KCHUNKS), 256, 0, stream>>>(xn_hi, xn_lo, wT_hi, wT_lo, h_part);
    k_hred<<<(int)(N / 256), 256, 0, stream>>>(h_part, h);

    // iteration 0 (CoPE)
    k_qkv<true><<<NROW, 192, 0, stream>>>(h, Wk, Wq, Wv, Wks, Wqs, Wvs, Wke, Wqe, Wve,
                                          q_hi, q_lo, k_hi, k_lo, vT);
    k_lg<<<dim3(T_TOT / 64, T_TOT / 64, BATCH), 256, 0, stream>>>(
        q_hi, q_lo, k_hi, k_lo, cT_hi, cT_lo, lint, csum);
    k_cscan<<<NROW / 256, 256, 0, stream>>>(csum, csumP, totalv);
    k_fattn0<<<dim3(NTBLK, NSC0, BATCH), 256, 0, stream>>>(
        q_hi, q_lo, k_hi, k_lo, vT, lint, csumP, totalv, fM, fD, fO);
    k_fmerge<<<BATCH * NTBLK, 256, 0, stream>>>(fM, fD, fO, mem1);

    // iteration 1 (plain causal)
    k_qkv<false><<<NROW, 192, 0, stream>>>(mem1, Wk, Wq, Wv, Wks, Wqs, Wvs, Wke, Wqe, Wve,
                                           q_hi, q_lo, k_hi, k_lo, vT);
    k_fattn1s<<<dim3(NTBLK, NSC0, BATCH), 256, 0, stream>>>(q_hi, k_hi, vT, fM, fD, fO);
    k_fmerge<<<BATCH * NTBLK, 256, 0, stream>>>(fM, fD, fO, out);
}